// Round 1
// baseline (320.919 us; speedup 1.0000x reference)
//
#include <hip/hip_runtime.h>
#include <hip/hip_bf16.h>
#include <cstdint>

// ---------------- types ----------------
typedef __attribute__((ext_vector_type(8))) _Float16 half8;
typedef __attribute__((ext_vector_type(4))) _Float16 half4;
typedef __attribute__((ext_vector_type(4))) float f32x4;

#define N_NODES 20000
#define N_EDGES 320000
#define IN_DIM 512
#define HID 256
#define N_GRAPHS 256

// ---------------- kernels ----------------

// x (fp32, N*512) -> f16, vectorized x4
__global__ __launch_bounds__(256) void convert_x_kernel(const float* __restrict__ x,
                                                        _Float16* __restrict__ xh, int n4) {
    int i = blockIdx.x * blockDim.x + threadIdx.x;
    if (i >= n4) return;
    float4 v = reinterpret_cast<const float4*>(x)[i];
    half4 o;
    o[0] = (_Float16)v.x; o[1] = (_Float16)v.y; o[2] = (_Float16)v.z; o[3] = (_Float16)v.w;
    reinterpret_cast<half4*>(xh)[i] = o;
}

// W [K=512][H=256] fp32 -> Wt [H][K] f16 (transposed so B-fragments are k-contiguous)
__global__ __launch_bounds__(256) void convert_w_kernel(const float* __restrict__ W,
                                                        _Float16* __restrict__ wt) {
    int t = blockIdx.x * blockDim.x + threadIdx.x;   // t = n*512 + k, t < 131072
    int n = t >> 9;
    int k = t & 511;
    wt[t] = (_Float16)W[k * HID + n];
}

// in-degree histogram over dst
__global__ __launch_bounds__(256) void hist_kernel(const int* __restrict__ dst,
                                                   int* __restrict__ ecnt, int E) {
    int e = blockIdx.x * blockDim.x + threadIdx.x;
    if (e < E) atomicAdd(&ecnt[dst[e]], 1);
}

// dinv = rsqrt(deg), deg = in-degree + 1 (self loop) >= 1 always
__global__ __launch_bounds__(256) void dinv_kernel(const int* __restrict__ ecnt,
                                                   float* __restrict__ dinv, int N) {
    int v = blockIdx.x * blockDim.x + threadIdx.x;
    if (v < N) dinv[v] = rsqrtf((float)(ecnt[v] + 1));
}

// single-block exclusive scan of ecnt[0..N) -> offsets[0..N]
__global__ __launch_bounds__(1024) void scan_kernel(const int* __restrict__ ecnt,
                                                    int* __restrict__ offsets, int N) {
    __shared__ int lds[1024];
    int t = threadIdx.x;
    const int CH = 20;                       // 1024*20 = 20480 >= 20000
    int base = t * CH;
    int s = 0;
    for (int i = 0; i < CH; ++i) {
        int idx = base + i;
        if (idx < N) s += ecnt[idx];
    }
    lds[t] = s;
    __syncthreads();
    int incl = s;
    for (int off = 1; off < 1024; off <<= 1) {
        int add = (t >= off) ? lds[t - off] : 0;
        __syncthreads();
        incl += add;
        lds[t] = incl;
        __syncthreads();
    }
    int run = incl - s;                      // exclusive prefix for this thread's chunk
    for (int i = 0; i < CH; ++i) {
        int idx = base + i;
        if (idx < N) {
            offsets[idx] = run;
            run += ecnt[idx];
        }
    }
    if (t == 1023) offsets[N] = incl;        // total edge count
}

// scatter edges into CSR buckets keyed by dst; store src id + precomputed norm
__global__ __launch_bounds__(256) void csr_fill_kernel(const int* __restrict__ src,
                                                       const int* __restrict__ dst,
                                                       const float* __restrict__ dinv,
                                                       const int* __restrict__ offsets,
                                                       int* __restrict__ cnt2,
                                                       int* __restrict__ csr_src,
                                                       float* __restrict__ csr_w, int E) {
    int e = blockIdx.x * blockDim.x + threadIdx.x;
    if (e >= E) return;
    int s = src[e], d = dst[e];
    int slot = offsets[d] + atomicAdd(&cnt2[d], 1);
    csr_src[slot] = s;
    csr_w[slot] = dinv[s] * dinv[d];
}

// h = x @ W via f16 MFMA 16x16x32. Block = 4 waves, each wave does a 16-row strip
// across the full 256-col output (16 MFMA tiles). Frags loaded straight from
// global (B working set 16 KB/k-step -> L1-resident).
__global__ __launch_bounds__(256) void gemm_kernel(const _Float16* __restrict__ xh,
                                                   const _Float16* __restrict__ wt,
                                                   float* __restrict__ h, int M) {
    const int K = IN_DIM;
    int wave = threadIdx.x >> 6;
    int lane = threadIdx.x & 63;
    int col  = lane & 15;
    int quad = lane >> 4;
    int row0 = blockIdx.x * 64 + wave * 16;

    f32x4 acc[16];
#pragma unroll
    for (int i = 0; i < 16; ++i) acc[i] = (f32x4){0.f, 0.f, 0.f, 0.f};

    int arow = row0 + col;
    if (arow >= M) arow = M - 1;             // clamp; stores are guarded
    const _Float16* aptr = xh + (size_t)arow * K + quad * 8;

    for (int k0 = 0; k0 < K; k0 += 32) {
        half8 a = *reinterpret_cast<const half8*>(aptr + k0);
#pragma unroll
        for (int nt = 0; nt < 16; ++nt) {
            half8 b = *reinterpret_cast<const half8*>(
                wt + (size_t)(nt * 16 + col) * K + k0 + quad * 8);
            acc[nt] = __builtin_amdgcn_mfma_f32_16x16x32_f16(a, b, acc[nt], 0, 0, 0);
        }
    }

    int orow0 = row0 + quad * 4;             // C/D: row=(lane>>4)*4+reg, col=lane&15
#pragma unroll
    for (int nt = 0; nt < 16; ++nt) {
#pragma unroll
        for (int r = 0; r < 4; ++r) {
            int rr = orow0 + r;
            if (rr < M) h[(size_t)rr * HID + nt * 16 + col] = acc[nt][r];
        }
    }
}

// one block per node; thread = feature. acc = dinv[v]^2*h[v] + sum_e norm*h[src].
// Fused: relu(+bias) then atomic pool into per-graph sums.
__global__ __launch_bounds__(256) void aggregate_kernel(const float* __restrict__ h,
                                                        const float* __restrict__ bias,
                                                        const float* __restrict__ dinv,
                                                        const int* __restrict__ offsets,
                                                        const int* __restrict__ csr_src,
                                                        const float* __restrict__ csr_w,
                                                        const int* __restrict__ batch,
                                                        float* __restrict__ sums,
                                                        int* __restrict__ counts) {
    int v = blockIdx.x;
    int f = threadIdx.x;
    float dv = dinv[v];
    float acc = dv * dv * h[(size_t)v * HID + f];
    int beg = offsets[v], end = offsets[v + 1];

    __shared__ int   s_src[256];
    __shared__ float s_w[256];
    for (int base = beg; base < end; base += 256) {
        int n = min(256, end - base);
        if (f < n) {
            s_src[f] = csr_src[base + f];
            s_w[f]   = csr_w[base + f];
        }
        __syncthreads();
        int j = 0;
        for (; j + 4 <= n; j += 4) {
            int   s0 = s_src[j],   s1 = s_src[j+1], s2 = s_src[j+2], s3 = s_src[j+3];
            float w0 = s_w[j],     w1 = s_w[j+1],   w2 = s_w[j+2],   w3 = s_w[j+3];
            float h0 = h[(size_t)s0 * HID + f];
            float h1 = h[(size_t)s1 * HID + f];
            float h2 = h[(size_t)s2 * HID + f];
            float h3 = h[(size_t)s3 * HID + f];
            acc += w0 * h0 + w1 * h1 + w2 * h2 + w3 * h3;
        }
        for (; j < n; ++j) acc += s_w[j] * h[(size_t)s_src[j] * HID + f];
        __syncthreads();
    }

    float xr = fmaxf(acc + bias[f], 0.0f);
    int g = batch[v];
    atomicAdd(&sums[(size_t)g * HID + f], xr);
    if (f == 0) atomicAdd(&counts[g], 1);
}

// one block per graph: pooled = sums/count, dot with lin_w, + lin_b, sigmoid
__global__ __launch_bounds__(256) void head_kernel(const float* __restrict__ sums,
                                                   const int* __restrict__ counts,
                                                   const float* __restrict__ lin_w,
                                                   const float* __restrict__ lin_b,
                                                   float* __restrict__ out) {
    int g = blockIdx.x;
    int f = threadIdx.x;
    float c = (float)counts[g];
    if (c < 1.f) c = 1.f;
    float v = (sums[(size_t)g * HID + f] / c) * lin_w[f];
#pragma unroll
    for (int off = 32; off >= 1; off >>= 1) v += __shfl_down(v, off, 64);
    __shared__ float red[4];
    if ((f & 63) == 0) red[f >> 6] = v;
    __syncthreads();
    if (f == 0) {
        float s = red[0] + red[1] + red[2] + red[3] + lin_b[0];
        out[g] = 1.0f / (1.0f + expf(-s));
    }
}

// ---------------- launch ----------------
extern "C" void kernel_launch(void* const* d_in, const int* in_sizes, int n_in,
                              void* d_out, int out_size, void* d_ws, size_t ws_size,
                              hipStream_t stream) {
    const float* x     = (const float*)d_in[0];
    const int*   edge  = (const int*)d_in[1];    // [2][E] flat: first E = src, next E = dst
    const int*   batch = (const int*)d_in[2];
    const float* W     = (const float*)d_in[3];
    const float* b     = (const float*)d_in[4];
    const float* lin_w = (const float*)d_in[5];
    const float* lin_b = (const float*)d_in[6];
    float*       out   = (float*)d_out;

    const int N = N_NODES, E = N_EDGES, G = N_GRAPHS, K = IN_DIM, H = HID;
    const int* src = edge;
    const int* dst = edge + E;

    char* p = (char*)d_ws;
    auto alloc = [&](size_t bytes) {
        char* r = p;
        p += (bytes + 255) & ~(size_t)255;
        return r;
    };
    _Float16* xh      = (_Float16*)alloc((size_t)N * K * 2);
    _Float16* wt      = (_Float16*)alloc((size_t)H * K * 2);
    float*    h       = (float*)alloc((size_t)N * H * 4);
    int*      ecnt    = (int*)alloc((size_t)N * 4);
    float*    dinv    = (float*)alloc((size_t)N * 4);
    int*      offsets = (int*)alloc((size_t)(N + 1) * 4);
    int*      cnt2    = (int*)alloc((size_t)N * 4);
    int*      csr_src = (int*)alloc((size_t)E * 4);
    float*    csr_w   = (float*)alloc((size_t)E * 4);
    float*    sums    = (float*)alloc((size_t)G * H * 4);
    int*      counts  = (int*)alloc((size_t)G * 4);

    hipMemsetAsync(ecnt,   0, (size_t)N * 4, stream);
    hipMemsetAsync(cnt2,   0, (size_t)N * 4, stream);
    hipMemsetAsync(sums,   0, (size_t)G * H * 4, stream);
    hipMemsetAsync(counts, 0, (size_t)G * 4, stream);

    convert_x_kernel<<<(N * K / 4 + 255) / 256, 256, 0, stream>>>(x, xh, N * K / 4);
    convert_w_kernel<<<(H * K + 255) / 256, 256, 0, stream>>>(W, wt);
    hist_kernel<<<(E + 255) / 256, 256, 0, stream>>>(dst, ecnt, E);
    dinv_kernel<<<(N + 255) / 256, 256, 0, stream>>>(ecnt, dinv, N);
    scan_kernel<<<1, 1024, 0, stream>>>(ecnt, offsets, N);
    csr_fill_kernel<<<(E + 255) / 256, 256, 0, stream>>>(src, dst, dinv, offsets, cnt2,
                                                         csr_src, csr_w, E);
    gemm_kernel<<<(N + 63) / 64, 256, 0, stream>>>(xh, wt, h, N);
    aggregate_kernel<<<N, 256, 0, stream>>>(h, b, dinv, offsets, csr_src, csr_w,
                                            batch, sums, counts);
    head_kernel<<<G, 256, 0, stream>>>(sums, counts, lin_w, lin_b, out);
}

// Round 2
// 222.901 us; speedup vs baseline: 1.4397x; 1.4397x over previous
//
#include <hip/hip_runtime.h>
#include <hip/hip_bf16.h>
#include <cstdint>

typedef __attribute__((ext_vector_type(8))) _Float16 half8;
typedef __attribute__((ext_vector_type(4))) float f32x4;

#define N_NODES 20000
#define N_EDGES 320000
#define IN_DIM 512
#define HID 256
#define N_GRAPHS 256
#define NPB 8            // nodes per aggregate block (N divisible by 8)
#define ECH 1024         // edge-staging chunk in LDS

// ---- prep: W transpose->f16  +  in-degree hist over dst  +  batch hist ----
#define PREP_W   (IN_DIM * HID)            // 131072
#define PREP_E   (PREP_W + N_EDGES)        // 451072
#define PREP_B   (PREP_E + N_NODES)        // 471072
__global__ __launch_bounds__(256) void prep_kernel(const float* __restrict__ W,
                                                   const int* __restrict__ dst,
                                                   const int* __restrict__ batch,
                                                   _Float16* __restrict__ wt,
                                                   int* __restrict__ ecnt,
                                                   int* __restrict__ counts) {
    int t = blockIdx.x * 256 + threadIdx.x;
    if (t < PREP_W) {
        // wt[n*512+k] = W[k*256+n]
        wt[t] = (_Float16)W[(t & 511) * HID + (t >> 9)];
    } else if (t < PREP_E) {
        atomicAdd(&ecnt[dst[t - PREP_W]], 1);
    } else if (t < PREP_B) {
        atomicAdd(&counts[batch[t - PREP_E]], 1);
    }
}

// ---- single-block scan of ecnt -> offsets[0..N], fused dinv ----
__global__ __launch_bounds__(1024) void scan_dinv_kernel(const int* __restrict__ ecnt,
                                                         int* __restrict__ offsets,
                                                         float* __restrict__ dinv) {
    __shared__ int lds[1024];
    int t = threadIdx.x;
    const int CHS = 20;                    // 1024*20 >= 20000; t<1000 fully in-range
    int base = t * CHS;
    int vals[CHS];
    int s = 0;
    if (t < 1000) {
        const int4* p = reinterpret_cast<const int4*>(ecnt + base);
#pragma unroll
        for (int i = 0; i < 5; ++i) {
            int4 v = p[i];
            vals[4*i+0] = v.x; vals[4*i+1] = v.y; vals[4*i+2] = v.z; vals[4*i+3] = v.w;
        }
#pragma unroll
        for (int i = 0; i < CHS; ++i) s += vals[i];
    }
    lds[t] = s;
    __syncthreads();
    int incl = s;
    for (int off = 1; off < 1024; off <<= 1) {
        int add = (t >= off) ? lds[t - off] : 0;
        __syncthreads();
        incl += add;
        lds[t] = incl;
        __syncthreads();
    }
    if (t < 1000) {
        int run = incl - s;
#pragma unroll
        for (int i = 0; i < CHS; ++i) {
            int idx = base + i;
            offsets[idx] = run;
            dinv[idx] = rsqrtf((float)(vals[i] + 1));
            run += vals[i];
        }
    }
    if (t == 1023) offsets[N_NODES] = incl;
}

// ---- scatter edges into CSR buckets keyed by dst ----
__global__ __launch_bounds__(256) void csr_fill_kernel(const int* __restrict__ src,
                                                       const int* __restrict__ dst,
                                                       const float* __restrict__ dinv,
                                                       const int* __restrict__ offsets,
                                                       int* __restrict__ cnt2,
                                                       int* __restrict__ csr_src,
                                                       float* __restrict__ csr_w, int E) {
    int e = blockIdx.x * blockDim.x + threadIdx.x;
    if (e >= E) return;
    int s = src[e], d = dst[e];
    int slot = offsets[d] + atomicAdd(&cnt2[d], 1);
    csr_src[slot] = s;
    csr_w[slot] = dinv[s] * dinv[d];
}

// ---- h16 = f16(x @ W): A fp32 from global (converted in-reg), B staged in LDS ----
__global__ __launch_bounds__(256) void gemm_kernel(const float* __restrict__ x,
                                                   const _Float16* __restrict__ wt,
                                                   _Float16* __restrict__ h16, int M) {
    __shared__ _Float16 bsl[16 * 16 * 32];   // 16 KB: [n-tile][col][k32]
    const int K = IN_DIM;
    int t    = threadIdx.x;
    int wave = t >> 6;
    int lane = t & 63;
    int col  = lane & 15;
    int quad = lane >> 4;
    int row0 = blockIdx.x * 64 + wave * 16;

    f32x4 acc[16];
#pragma unroll
    for (int i = 0; i < 16; ++i) acc[i] = (f32x4){0.f, 0.f, 0.f, 0.f};

    int arow = row0 + col;
    if (arow >= M) arow = M - 1;
    const float* aptr = x + (size_t)arow * K + quad * 8;
    const uint4* wsrc = reinterpret_cast<const uint4*>(wt + (size_t)t * K); // 8 f16 / uint4

    for (int k0 = 0; k0 < K; k0 += 32) {
        __syncthreads();
        {   // stage B slice: thread t copies wt[t*512 + k0 .. +32)
            uint4* d = reinterpret_cast<uint4*>(&bsl[t * 32]);
            const uint4* s = wsrc + (k0 >> 3);
            d[0] = s[0]; d[1] = s[1]; d[2] = s[2]; d[3] = s[3];
        }
        __syncthreads();
        float4 a0 = *reinterpret_cast<const float4*>(aptr + k0);
        float4 a1 = *reinterpret_cast<const float4*>(aptr + k0 + 4);
        half8 a;
        a[0] = (_Float16)a0.x; a[1] = (_Float16)a0.y; a[2] = (_Float16)a0.z; a[3] = (_Float16)a0.w;
        a[4] = (_Float16)a1.x; a[5] = (_Float16)a1.y; a[6] = (_Float16)a1.z; a[7] = (_Float16)a1.w;
#pragma unroll
        for (int nt = 0; nt < 16; ++nt) {
            half8 b = *reinterpret_cast<const half8*>(&bsl[(nt * 16 + col) * 32 + quad * 8]);
            acc[nt] = __builtin_amdgcn_mfma_f32_16x16x32_f16(a, b, acc[nt], 0, 0, 0);
        }
    }

    int orow0 = row0 + quad * 4;             // C/D: row=(lane>>4)*4+reg, col=lane&15
#pragma unroll
    for (int nt = 0; nt < 16; ++nt) {
#pragma unroll
        for (int r = 0; r < 4; ++r) {
            int rr = orow0 + r;
            if (rr < M) h16[(size_t)rr * HID + nt * 16 + col] = (_Float16)acc[nt][r];
        }
    }
}

// ---- aggregate 8 consecutive nodes/block; f16 gathers; register pre-pooling ----
__global__ __launch_bounds__(256) void aggregate_kernel(const _Float16* __restrict__ h16,
                                                        const float* __restrict__ bias,
                                                        const float* __restrict__ dinv,
                                                        const int* __restrict__ offsets,
                                                        const int* __restrict__ csr_src,
                                                        const float* __restrict__ csr_w,
                                                        const int* __restrict__ batch,
                                                        float* __restrict__ sums) {
    __shared__ int   s_src[ECH];
    __shared__ float s_w[ECH];
    int v0 = blockIdx.x * NPB;
    int f  = threadIdx.x;
    float bf = bias[f];

    int off[NPB + 1];
#pragma unroll
    for (int i = 0; i <= NPB; ++i) off[i] = offsets[v0 + i];

    float acc[NPB];
#pragma unroll
    for (int i = 0; i < NPB; ++i) {
        int v = v0 + i;
        float dv = dinv[v];
        acc[i] = dv * dv * (float)h16[(size_t)v * HID + f];
    }

    int beg0 = off[0], end0 = off[NPB];
    for (int cb = beg0; cb < end0; cb += ECH) {
        int n = min(ECH, end0 - cb);
        for (int tt = f; tt < n; tt += 256) {
            s_src[tt] = csr_src[cb + tt];
            s_w[tt]   = csr_w[cb + tt];
        }
        __syncthreads();
#pragma unroll
        for (int i = 0; i < NPB; ++i) {
            int lo = off[i] - cb;     if (lo < 0) lo = 0;
            int hi = off[i + 1] - cb; if (hi > n) hi = n;
            float a = acc[i];
            int j = lo;
            for (; j + 4 <= hi; j += 4) {
                int   s0 = s_src[j],   s1 = s_src[j+1], s2 = s_src[j+2], s3 = s_src[j+3];
                float w0 = s_w[j],     w1 = s_w[j+1],   w2 = s_w[j+2],   w3 = s_w[j+3];
                float h0 = (float)h16[(size_t)s0 * HID + f];
                float h1 = (float)h16[(size_t)s1 * HID + f];
                float h2 = (float)h16[(size_t)s2 * HID + f];
                float h3 = (float)h16[(size_t)s3 * HID + f];
                a += w0 * h0 + w1 * h1 + w2 * h2 + w3 * h3;
            }
            for (; j < hi; ++j) a += s_w[j] * (float)h16[(size_t)s_src[j] * HID + f];
            acc[i] = a;
        }
        __syncthreads();
    }

    // relu(+bias) then register pre-pooling: batch is sorted, flush on graph change
    float pooled = 0.f;
    int cur_g = batch[v0];
#pragma unroll
    for (int i = 0; i < NPB; ++i) {
        float xr = fmaxf(acc[i] + bf, 0.f);
        int g = batch[v0 + i];
        if (g != cur_g) {
            atomicAdd(&sums[(size_t)cur_g * HID + f], pooled);
            pooled = 0.f;
            cur_g = g;
        }
        pooled += xr;
    }
    atomicAdd(&sums[(size_t)cur_g * HID + f], pooled);
}

// ---- head: pooled = sums/count, dot lin_w, sigmoid ----
__global__ __launch_bounds__(256) void head_kernel(const float* __restrict__ sums,
                                                   const int* __restrict__ counts,
                                                   const float* __restrict__ lin_w,
                                                   const float* __restrict__ lin_b,
                                                   float* __restrict__ out) {
    int g = blockIdx.x;
    int f = threadIdx.x;
    float c = (float)counts[g];
    if (c < 1.f) c = 1.f;
    float v = (sums[(size_t)g * HID + f] / c) * lin_w[f];
#pragma unroll
    for (int off = 32; off >= 1; off >>= 1) v += __shfl_down(v, off, 64);
    __shared__ float red[4];
    if ((f & 63) == 0) red[f >> 6] = v;
    __syncthreads();
    if (f == 0) {
        float s = red[0] + red[1] + red[2] + red[3] + lin_b[0];
        out[g] = 1.0f / (1.0f + expf(-s));
    }
}

// ---------------- launch ----------------
extern "C" void kernel_launch(void* const* d_in, const int* in_sizes, int n_in,
                              void* d_out, int out_size, void* d_ws, size_t ws_size,
                              hipStream_t stream) {
    const float* x     = (const float*)d_in[0];
    const int*   edge  = (const int*)d_in[1];    // [2][E]: first E = src, next E = dst
    const int*   batch = (const int*)d_in[2];
    const float* W     = (const float*)d_in[3];
    const float* b     = (const float*)d_in[4];
    const float* lin_w = (const float*)d_in[5];
    const float* lin_b = (const float*)d_in[6];
    float*       out   = (float*)d_out;

    const int N = N_NODES, E = N_EDGES, G = N_GRAPHS, K = IN_DIM, H = HID;
    const int* src = edge;
    const int* dst = edge + E;

    char* p = (char*)d_ws;
    auto alloc = [&](size_t bytes) {
        char* r = p;
        p += (bytes + 255) & ~(size_t)255;
        return r;
    };
    _Float16* wt      = (_Float16*)alloc((size_t)H * K * 2);
    _Float16* h16     = (_Float16*)alloc((size_t)N * H * 2);
    float*    dinv    = (float*)alloc((size_t)N * 4);
    int*      offsets = (int*)alloc((size_t)(N + 1) * 4);
    int*      csr_src = (int*)alloc((size_t)E * 4);
    float*    csr_w   = (float*)alloc((size_t)E * 4);
    // zero-region: contiguous so ONE memset covers all
    char* z0 = p;
    int*      ecnt    = (int*)alloc((size_t)N * 4);
    int*      cnt2    = (int*)alloc((size_t)N * 4);
    float*    sums    = (float*)alloc((size_t)G * H * 4);
    int*      counts  = (int*)alloc((size_t)G * 4);
    size_t zbytes = (size_t)(p - z0);

    hipMemsetAsync(z0, 0, zbytes, stream);

    prep_kernel<<<(PREP_B + 255) / 256, 256, 0, stream>>>(W, dst, batch, wt, ecnt, counts);
    scan_dinv_kernel<<<1, 1024, 0, stream>>>(ecnt, offsets, dinv);
    csr_fill_kernel<<<(E + 255) / 256, 256, 0, stream>>>(src, dst, dinv, offsets, cnt2,
                                                         csr_src, csr_w, E);
    gemm_kernel<<<(N + 63) / 64, 256, 0, stream>>>(x, wt, h16, N);
    aggregate_kernel<<<N / NPB, 256, 0, stream>>>(h16, b, dinv, offsets, csr_src, csr_w,
                                                  batch, sums);
    head_kernel<<<G, 256, 0, stream>>>(sums, counts, lin_w, lin_b, out);
}

// Round 3
// 210.493 us; speedup vs baseline: 1.5246x; 1.0589x over previous
//
#include <hip/hip_runtime.h>
#include <hip/hip_bf16.h>
#include <cstdint>

typedef __attribute__((ext_vector_type(8))) _Float16 half8;
typedef __attribute__((ext_vector_type(2))) _Float16 h2;
typedef __attribute__((ext_vector_type(4))) float f32x4;

#define N_NODES 20000
#define N_EDGES 320000
#define IN_DIM 512
#define HID 256
#define N_GRAPHS 256
#define NPB 8            // nodes per aggregate block
#define ECH 1024         // edge-staging chunk in LDS (int2 -> 8 KB)

// ---- prep: W transpose->f16  +  in-degree hist over dst  +  batch hist ----
#define PREP_W   (IN_DIM * HID)            // 131072
#define PREP_E   (PREP_W + N_EDGES)        // 451072
#define PREP_B   (PREP_E + N_NODES)        // 471072
__global__ __launch_bounds__(256) void prep_kernel(const float* __restrict__ W,
                                                   const int* __restrict__ dst,
                                                   const int* __restrict__ batch,
                                                   _Float16* __restrict__ wt,
                                                   int* __restrict__ ecnt,
                                                   int* __restrict__ counts) {
    int t = blockIdx.x * 256 + threadIdx.x;
    if (t < PREP_W) {
        wt[t] = (_Float16)W[(t & 511) * HID + (t >> 9)];   // wt[n*512+k] = W[k*256+n]
    } else if (t < PREP_E) {
        atomicAdd(&ecnt[dst[t - PREP_W]], 1);
    } else if (t < PREP_B) {
        atomicAdd(&counts[batch[t - PREP_E]], 1);
    }
}

// ---- single-block scan of ecnt -> offsets[0..N], fused dinv; shfl wave-scans ----
__global__ __launch_bounds__(1024) void scan_dinv_kernel(const int* __restrict__ ecnt,
                                                         int* __restrict__ offsets,
                                                         float* __restrict__ dinv) {
    __shared__ int wsum[16];
    int t = threadIdx.x;
    int lane = t & 63, wid = t >> 6;
    const int CHS = 20;                    // 1024*20 >= 20000; t<1000 fully in-range
    int base = t * CHS;
    int vals[CHS];
    int s = 0;
    if (t < 1000) {
        const int4* p = reinterpret_cast<const int4*>(ecnt + base);
#pragma unroll
        for (int i = 0; i < 5; ++i) {
            int4 v = p[i];
            vals[4*i+0] = v.x; vals[4*i+1] = v.y; vals[4*i+2] = v.z; vals[4*i+3] = v.w;
        }
#pragma unroll
        for (int i = 0; i < CHS; ++i) s += vals[i];
    }
    // wave-inclusive scan via shfl
    int incl = s;
#pragma unroll
    for (int off = 1; off < 64; off <<= 1) {
        int u = __shfl_up(incl, off, 64);
        if (lane >= off) incl += u;
    }
    if (lane == 63) wsum[wid] = incl;
    __syncthreads();
    if (t < 16) {
        int v = wsum[t];
#pragma unroll
        for (int off = 1; off < 16; off <<= 1) {
            int u = __shfl_up(v, off, 16);
            if (t >= off) v += u;
        }
        wsum[t] = v;                       // inclusive wave prefix
    }
    __syncthreads();
    int woff = (wid == 0) ? 0 : wsum[wid - 1];
    if (t < 1000) {
        int run = woff + incl - s;         // exclusive prefix for this thread's chunk
#pragma unroll
        for (int i = 0; i < CHS; ++i) {
            int idx = base + i;
            offsets[idx] = run;
            dinv[idx] = rsqrtf((float)(vals[i] + 1));
            run += vals[i];
        }
    }
    if (t == 1023) offsets[N_NODES] = wsum[15];
}

// ---- scatter edges into CSR buckets keyed by dst; packed (src, w) int2 ----
__global__ __launch_bounds__(256) void csr_fill_kernel(const int* __restrict__ src,
                                                       const int* __restrict__ dst,
                                                       const float* __restrict__ dinv,
                                                       const int* __restrict__ offsets,
                                                       int* __restrict__ cnt2,
                                                       int2* __restrict__ csr, int E) {
    int e = blockIdx.x * blockDim.x + threadIdx.x;
    if (e >= E) return;
    int s = src[e], d = dst[e];
    int slot = offsets[d] + atomicAdd(&cnt2[d], 1);
    int2 pk;
    pk.x = s;
    pk.y = __float_as_int(dinv[s] * dinv[d]);
    csr[slot] = pk;
}

// ---- h16 = f16(x @ W): reg-double-buffered A (global fp32) and B (LDS stage) ----
__global__ __launch_bounds__(256) void gemm_kernel(const float* __restrict__ x,
                                                   const _Float16* __restrict__ wt,
                                                   _Float16* __restrict__ h16, int M) {
    __shared__ _Float16 bsl[16 * 16 * 32];   // 16 KB: [n-tile][col][k32]
    const int K = IN_DIM;
    int t    = threadIdx.x;
    int wave = t >> 6;
    int lane = t & 63;
    int col  = lane & 15;
    int quad = lane >> 4;
    int row0 = blockIdx.x * 64 + wave * 16;

    f32x4 acc[16];
#pragma unroll
    for (int i = 0; i < 16; ++i) acc[i] = (f32x4){0.f, 0.f, 0.f, 0.f};

    int arow = row0 + col;
    if (arow >= M) arow = M - 1;
    const float* aptr = x + (size_t)arow * K + quad * 8;
    const uint4* wsrc = reinterpret_cast<const uint4*>(wt + (size_t)t * K); // 8 f16/uint4

    float4 pa0 = *reinterpret_cast<const float4*>(aptr);
    float4 pa1 = *reinterpret_cast<const float4*>(aptr + 4);
    uint4 b0 = wsrc[0], b1 = wsrc[1], b2 = wsrc[2], b3 = wsrc[3];

    for (int k0 = 0; k0 < K; k0 += 32) {
        __syncthreads();
        {
            uint4* d = reinterpret_cast<uint4*>(&bsl[t * 32]);
            d[0] = b0; d[1] = b1; d[2] = b2; d[3] = b3;
        }
        __syncthreads();
        half8 a;
        a[0] = (_Float16)pa0.x; a[1] = (_Float16)pa0.y;
        a[2] = (_Float16)pa0.z; a[3] = (_Float16)pa0.w;
        a[4] = (_Float16)pa1.x; a[5] = (_Float16)pa1.y;
        a[6] = (_Float16)pa1.z; a[7] = (_Float16)pa1.w;
        if (k0 + 32 < K) {                  // prefetch next k-step into regs
            const float* ap = aptr + k0 + 32;
            pa0 = *reinterpret_cast<const float4*>(ap);
            pa1 = *reinterpret_cast<const float4*>(ap + 4);
            const uint4* ws = wsrc + ((k0 + 32) >> 3);
            b0 = ws[0]; b1 = ws[1]; b2 = ws[2]; b3 = ws[3];
        }
#pragma unroll
        for (int nt = 0; nt < 16; ++nt) {
            half8 b = *reinterpret_cast<const half8*>(&bsl[(nt * 16 + col) * 32 + quad * 8]);
            acc[nt] = __builtin_amdgcn_mfma_f32_16x16x32_f16(a, b, acc[nt], 0, 0, 0);
        }
    }

    int orow0 = row0 + quad * 4;             // C/D: row=(lane>>4)*4+reg, col=lane&15
#pragma unroll
    for (int nt = 0; nt < 16; ++nt) {
#pragma unroll
        for (int r = 0; r < 4; ++r) {
            int rr = orow0 + r;
            if (rr < M) h16[(size_t)rr * HID + nt * 16 + col] = (_Float16)acc[nt][r];
        }
    }
}

// ---- aggregate: 2 groups x 4 nodes per block; half2 gathers (2 feat/thread) ----
__global__ __launch_bounds__(256) void aggregate_kernel(const _Float16* __restrict__ h16,
                                                        const float* __restrict__ bias,
                                                        const float* __restrict__ dinv,
                                                        const int* __restrict__ offsets,
                                                        const int2* __restrict__ csr,
                                                        const int* __restrict__ batch,
                                                        float* __restrict__ sums) {
    __shared__ int2 s_e[ECH];
    int v0  = blockIdx.x * NPB;
    int t   = threadIdx.x;
    int grp = t >> 7;                // waves {0,1} vs {2,3}
    int ft  = t & 127;               // features 2*ft, 2*ft+1
    int vg  = v0 + grp * 4;
    float bf0 = bias[2 * ft], bf1 = bias[2 * ft + 1];

    int off[5];
#pragma unroll
    for (int i = 0; i <= 4; ++i) off[i] = offsets[vg + i];
    int beg0 = offsets[v0], end0 = offsets[v0 + NPB];

    float a0[4], a1[4];
#pragma unroll
    for (int i = 0; i < 4; ++i) {
        int v = vg + i;
        float dv = dinv[v];
        float d2 = dv * dv;
        h2 hv = *reinterpret_cast<const h2*>(h16 + (size_t)v * HID + 2 * ft);
        a0[i] = d2 * (float)hv[0];
        a1[i] = d2 * (float)hv[1];
    }

    for (int cb = beg0; cb < end0; cb += ECH) {
        int n = min(ECH, end0 - cb);
        for (int tt = t; tt < n; tt += 256) s_e[tt] = csr[cb + tt];
        __syncthreads();
#pragma unroll
        for (int i = 0; i < 4; ++i) {
            int lo = off[i] - cb;     if (lo < 0) lo = 0;
            int hi = off[i + 1] - cb; if (hi > n) hi = n;
            float x0 = a0[i], x1 = a1[i];
            int j = lo;
            for (; j + 4 <= hi; j += 4) {
                int2 e0 = s_e[j], e1 = s_e[j+1], e2 = s_e[j+2], e3 = s_e[j+3];
                h2 q0 = *reinterpret_cast<const h2*>(h16 + (size_t)e0.x * HID + 2 * ft);
                h2 q1 = *reinterpret_cast<const h2*>(h16 + (size_t)e1.x * HID + 2 * ft);
                h2 q2 = *reinterpret_cast<const h2*>(h16 + (size_t)e2.x * HID + 2 * ft);
                h2 q3 = *reinterpret_cast<const h2*>(h16 + (size_t)e3.x * HID + 2 * ft);
                float w0 = __int_as_float(e0.y), w1 = __int_as_float(e1.y);
                float w2 = __int_as_float(e2.y), w3 = __int_as_float(e3.y);
                x0 += w0 * (float)q0[0] + w1 * (float)q1[0]
                    + w2 * (float)q2[0] + w3 * (float)q3[0];
                x1 += w0 * (float)q0[1] + w1 * (float)q1[1]
                    + w2 * (float)q2[1] + w3 * (float)q3[1];
            }
            for (; j < hi; ++j) {
                int2 e = s_e[j];
                h2 q = *reinterpret_cast<const h2*>(h16 + (size_t)e.x * HID + 2 * ft);
                float w = __int_as_float(e.y);
                x0 += w * (float)q[0];
                x1 += w * (float)q[1];
            }
            a0[i] = x0; a1[i] = x1;
        }
        __syncthreads();
    }

    // relu(+bias), register pre-pool per group (batch sorted), flush on change
    float p0 = 0.f, p1 = 0.f;
    int cur_g = batch[vg];
#pragma unroll
    for (int i = 0; i < 4; ++i) {
        float r0 = fmaxf(a0[i] + bf0, 0.f);
        float r1 = fmaxf(a1[i] + bf1, 0.f);
        int g = batch[vg + i];
        if (g != cur_g) {
            atomicAdd(&sums[(size_t)cur_g * HID + 2 * ft],     p0);
            atomicAdd(&sums[(size_t)cur_g * HID + 2 * ft + 1], p1);
            p0 = 0.f; p1 = 0.f; cur_g = g;
        }
        p0 += r0; p1 += r1;
    }
    atomicAdd(&sums[(size_t)cur_g * HID + 2 * ft],     p0);
    atomicAdd(&sums[(size_t)cur_g * HID + 2 * ft + 1], p1);
}

// ---- head: pooled = sums/count, dot lin_w, sigmoid ----
__global__ __launch_bounds__(256) void head_kernel(const float* __restrict__ sums,
                                                   const int* __restrict__ counts,
                                                   const float* __restrict__ lin_w,
                                                   const float* __restrict__ lin_b,
                                                   float* __restrict__ out) {
    int g = blockIdx.x;
    int f = threadIdx.x;
    float c = (float)counts[g];
    if (c < 1.f) c = 1.f;
    float v = (sums[(size_t)g * HID + f] / c) * lin_w[f];
#pragma unroll
    for (int off = 32; off >= 1; off >>= 1) v += __shfl_down(v, off, 64);
    __shared__ float red[4];
    if ((f & 63) == 0) red[f >> 6] = v;
    __syncthreads();
    if (f == 0) {
        float s = red[0] + red[1] + red[2] + red[3] + lin_b[0];
        out[g] = 1.0f / (1.0f + expf(-s));
    }
}

// ---------------- launch ----------------
extern "C" void kernel_launch(void* const* d_in, const int* in_sizes, int n_in,
                              void* d_out, int out_size, void* d_ws, size_t ws_size,
                              hipStream_t stream) {
    const float* x     = (const float*)d_in[0];
    const int*   edge  = (const int*)d_in[1];    // [2][E]: first E = src, next E = dst
    const int*   batch = (const int*)d_in[2];
    const float* W     = (const float*)d_in[3];
    const float* b     = (const float*)d_in[4];
    const float* lin_w = (const float*)d_in[5];
    const float* lin_b = (const float*)d_in[6];
    float*       out   = (float*)d_out;

    const int N = N_NODES, E = N_EDGES, G = N_GRAPHS, K = IN_DIM, H = HID;
    const int* src = edge;
    const int* dst = edge + E;

    char* p = (char*)d_ws;
    auto alloc = [&](size_t bytes) {
        char* r = p;
        p += (bytes + 255) & ~(size_t)255;
        return r;
    };
    _Float16* wt      = (_Float16*)alloc((size_t)H * K * 2);
    _Float16* h16     = (_Float16*)alloc((size_t)N * H * 2);
    float*    dinv    = (float*)alloc((size_t)N * 4);
    int*      offsets = (int*)alloc((size_t)(N + 1) * 4);
    int2*     csr     = (int2*)alloc((size_t)E * 8);
    // zero-region: contiguous so ONE memset covers all
    char* z0 = p;
    int*      ecnt    = (int*)alloc((size_t)N * 4);
    int*      cnt2    = (int*)alloc((size_t)N * 4);
    float*    sums    = (float*)alloc((size_t)G * H * 4);
    int*      counts  = (int*)alloc((size_t)G * 4);
    size_t zbytes = (size_t)(p - z0);

    hipMemsetAsync(z0, 0, zbytes, stream);

    prep_kernel<<<(PREP_B + 255) / 256, 256, 0, stream>>>(W, dst, batch, wt, ecnt, counts);
    scan_dinv_kernel<<<1, 1024, 0, stream>>>(ecnt, offsets, dinv);
    csr_fill_kernel<<<(E + 255) / 256, 256, 0, stream>>>(src, dst, dinv, offsets, cnt2,
                                                         csr, E);
    gemm_kernel<<<(N + 63) / 64, 256, 0, stream>>>(x, wt, h16, N);
    aggregate_kernel<<<N / NPB, 256, 0, stream>>>(h16, b, dinv, offsets, csr, batch, sums);
    head_kernel<<<G, 256, 0, stream>>>(sums, counts, lin_w, lin_b, out);
}